// Round 9
// baseline (81.641 us; speedup 1.0000x reference)
//
#include <hip/hip_runtime.h>
#include <hip/hip_bf16.h>

#define NB 16
#define NN 256
#define NH 8
#define ND 64
#define NT 5
#define HD 512   // NH*ND

typedef __bf16 bf16x8 __attribute__((ext_vector_type(8)));
typedef __bf16 bf16x4 __attribute__((ext_vector_type(4)));
typedef float  f32x4  __attribute__((ext_vector_type(4)));

__device__ __forceinline__ float4 ld4(const float* p) {
    return *reinterpret_cast<const float4*>(p);
}

__device__ __forceinline__ bf16x8 cvt8(float4 a, float4 b) {
    bf16x8 r;
    r[0] = (__bf16)a.x; r[1] = (__bf16)a.y; r[2] = (__bf16)a.z; r[3] = (__bf16)a.w;
    r[4] = (__bf16)b.x; r[5] = (__bf16)b.y; r[6] = (__bf16)b.z; r[7] = (__bf16)b.w;
    return r;
}

// Transpose a[(h*64+dd)*64*5 + e*5 + t] (fp32) -> wt[h][t][e][dd] (bf16).
__global__ void prep_w_kernel(const float* __restrict__ a, __bf16* __restrict__ wt) {
    int idx = blockIdx.x * 256 + threadIdx.x;
    if (idx >= NH * ND * ND * NT) return;
    int t  = idx % NT;
    int e  = (idx / NT) % ND;
    int dd = (idx / (NT * ND)) % ND;
    int h  = idx / (NT * ND * ND);
    wt[(((h * NT + t) * ND + e) * ND) + dd] = (__bf16)a[idx];
}

// ---------------- k1: T[b,h,t,i,e] = sum_dd src[b,i,h,dd] * W[h,dd,e,t] ----------------
// One wave per (b,h,it). No LDS, no barrier: load -> 40 MFMA -> store.
__global__ __launch_bounds__(64) void k1_transform(
    const float* __restrict__ src, const __bf16* __restrict__ wt,
    __bf16* __restrict__ T)
{
    const int bid = blockIdx.x;
    const int wg  = (bid & 7) * 256 + (bid >> 3);   // XCD-chunked, bijective (2048=8*256)
    const int it  = wg & 15;
    const int h   = (wg >> 4) & 7;
    const int b   = wg >> 7;
    const int i0  = it * 16;

    const int l  = threadIdx.x & 63;
    const int il = l & 15;
    const int kg = l >> 4;

    const float* sbase = src + (size_t)(b * NN + i0 + il) * HD + h * ND;
    float4 s0 = ld4(sbase + kg * 8);
    float4 s1 = ld4(sbase + kg * 8 + 4);
    float4 s2 = ld4(sbase + 32 + kg * 8);
    float4 s3 = ld4(sbase + 32 + kg * 8 + 4);
    bf16x8 af0 = cvt8(s0, s1);
    bf16x8 af1 = cvt8(s2, s3);

    #pragma unroll
    for (int t = 0; t < NT; ++t) {
        bf16x8 w0[4], w1[4];
        #pragma unroll
        for (int et = 0; et < 4; ++et) {
            const __bf16* wp = wt + (((h * NT + t) * ND + et * 16 + il) * ND) + kg * 8;
            w0[et] = *reinterpret_cast<const bf16x8*>(wp);
            w1[et] = *reinterpret_cast<const bf16x8*>(wp + 32);
        }
        __bf16* tb = T + ((size_t)((b * NH + h) * NT + t) * NN + i0 + il) * ND;
        #pragma unroll
        for (int et = 0; et < 4; ++et) {
            // A = W^T rows (m=e), B = src (n=i): D lane holds e=et*16+kg*4+r, i=il
            f32x4 pacc = {0.f, 0.f, 0.f, 0.f};
            pacc = __builtin_amdgcn_mfma_f32_16x16x32_bf16(w0[et], af0, pacc, 0, 0, 0);
            pacc = __builtin_amdgcn_mfma_f32_16x16x32_bf16(w1[et], af1, pacc, 0, 0, 0);
            bf16x4 pk;
            pk[0] = (__bf16)pacc[0];
            pk[1] = (__bf16)pacc[1];
            pk[2] = (__bf16)pacc[2];
            pk[3] = (__bf16)pacc[3];
            // NOTE: writes 8B at row (i0+il), cols et*16+kg*4 .. +3  (contiguous)
            *reinterpret_cast<bf16x4*>(tb + et * 16 + kg * 4) = pk;
        }
    }
}

// ---------------- k2: S[i,j] = select_t( T_t[i,:] . dst[j,:] ), mask, leaky ----------------
// One wave per (16i x 16j) tile. 15 independent loads, 10 MFMA, 1 store.
// No LDS, no barrier, no inter-phase dependence.
__global__ __launch_bounds__(256, 3) void k2_scores(
    const __bf16* __restrict__ T, const float* __restrict__ dst,
    const int* __restrict__ edges, float* __restrict__ out)
{
    const int bid = blockIdx.x;
    const int wg  = (bid & 7) * 1024 + (bid >> 3);  // XCD-chunked, bijective (8192=8*1024)
    const int b   = wg >> 9;
    const int rem = wg & 511;
    const int h   = rem >> 6;          // 0..7
    const int it  = (rem >> 2) & 15;   // 0..15
    const int jg  = rem & 3;           // 0..3
    const int i0  = it * 16;

    const int tid = threadIdx.x;
    const int w   = tid >> 6;
    const int l   = tid & 63;
    const int il  = l & 15;
    const int kg  = l >> 4;
    const int j0  = (jg * 4 + w) * 16;

    // ---- all loads issue before any use (15 independent VMEM ops) ----
    const float* dp = dst + (size_t)b * NN * HD + h * ND + (size_t)(j0 + il) * HD + kg * 8;
    float4 q0 = ld4(dp);
    float4 q1 = ld4(dp + 4);
    float4 q2 = ld4(dp + 32);
    float4 q3 = ld4(dp + 36);

    const int4 ce = *reinterpret_cast<const int4*>(
        edges + ((size_t)b * NN + i0 + il) * NN + j0 + kg * 4);

    const __bf16* Tb = T + (size_t)((b * NH + h) * NT) * NN * ND + (i0 + il) * ND;
    bf16x8 pa[NT][2];
    #pragma unroll
    for (int t = 0; t < NT; ++t) {
        #pragma unroll
        for (int ks = 0; ks < 2; ++ks) {
            pa[t][ks] = *reinterpret_cast<const bf16x8*>(
                Tb + (size_t)t * NN * ND + ks * 32 + kg * 8);
        }
    }

    // ---- compute ----
    const bf16x8 cb0 = cvt8(q0, q1);
    const bf16x8 cb1 = cvt8(q2, q3);

    f32x4 acc[NT];
    #pragma unroll
    for (int t = 0; t < NT; ++t) {
        acc[t] = (f32x4){0.f, 0.f, 0.f, 0.f};
        // A = dst rows (m=j), B = T (n=i): D lane holds j=kg*4+r, i=il
        acc[t] = __builtin_amdgcn_mfma_f32_16x16x32_bf16(cb0, pa[t][0], acc[t], 0, 0, 0);
        acc[t] = __builtin_amdgcn_mfma_f32_16x16x32_bf16(cb1, pa[t][1], acc[t], 0, 0, 0);
    }

    float4 o;
    #pragma unroll
    for (int r = 0; r < 4; ++r) {
        const int ev = (&ce.x)[r];
        float x;
        if (ev < 0) { x = -1e10f; }
        else {
            x = (ev == 0) ? acc[0][r]
              : (ev == 1) ? acc[1][r]
              : (ev == 2) ? acc[2][r]
              : (ev == 3) ? acc[3][r]
              :             acc[4][r];
        }
        (&o.x)[r] = (x >= 0.f) ? x : 0.2f * x;
    }
    *reinterpret_cast<float4*>(
        out + ((size_t)(b * NH + h) * NN + i0 + il) * NN + j0 + kg * 4) = o;
}

// ---------------- fallback (ws too small): R6 fused 1-wave kernel, araw path ----------------
__global__ __launch_bounds__(64, 3) void mhea_fused_fallback(
    const float* __restrict__ src, const float* __restrict__ dst,
    const float* __restrict__ araw, const int* __restrict__ edges,
    float* __restrict__ out)
{
    __shared__ __bf16 Plds[NT * 16 * 64];

    const int it = blockIdx.x;
    const int h  = blockIdx.y;
    const int b  = blockIdx.z;
    const int i0 = it * 16;

    const int l  = threadIdx.x & 63;
    const int il = l & 15;
    const int kg = l >> 4;

    const float* dbase = dst + (size_t)b * NN * HD + h * ND;
    const int*   erow  = edges + ((size_t)b * NN + i0 + il) * NN;
    const float* sbase = src + (size_t)(b * NN + i0 + il) * HD + h * ND;

    float4 s0 = ld4(sbase + kg * 8);
    float4 s1 = ld4(sbase + kg * 8 + 4);
    float4 s2 = ld4(sbase + 32 + kg * 8);
    float4 s3 = ld4(sbase + 32 + kg * 8 + 4);
    bf16x8 af0 = cvt8(s0, s1);
    bf16x8 af1 = cvt8(s2, s3);

    #pragma unroll
    for (int t = 0; t < NT; ++t) {
        #pragma unroll
        for (int et = 0; et < 4; ++et) {
            bf16x8 w0, w1;
            #pragma unroll
            for (int jj = 0; jj < 8; ++jj) {
                const int e = et * 16 + il;
                w0[jj] = (__bf16)araw[((size_t)(h * ND + kg * 8 + jj) * ND + e) * NT + t];
                w1[jj] = (__bf16)araw[((size_t)(h * ND + kg * 8 + jj + 32) * ND + e) * NT + t];
            }
            f32x4 pacc = {0.f, 0.f, 0.f, 0.f};
            pacc = __builtin_amdgcn_mfma_f32_16x16x32_bf16(w0, af0, pacc, 0, 0, 0);
            pacc = __builtin_amdgcn_mfma_f32_16x16x32_bf16(w1, af1, pacc, 0, 0, 0);
            bf16x4 pk;
            pk[0] = (__bf16)pacc[0];
            pk[1] = (__bf16)pacc[1];
            pk[2] = (__bf16)pacc[2];
            pk[3] = (__bf16)pacc[3];
            const int elem = (et * 16 + kg * 4) ^ ((il & 7) << 3);
            *reinterpret_cast<bf16x4*>(&Plds[t * 1024 + il * 64 + elem]) = pk;
        }
    }

    bf16x8 pa[NT][2];
    #pragma unroll
    for (int t = 0; t < NT; ++t) {
        #pragma unroll
        for (int ks = 0; ks < 2; ++ks) {
            const int elem = (ks * 32 + kg * 8) ^ ((il & 7) << 3);
            pa[t][ks] = *reinterpret_cast<const bf16x8*>(&Plds[t * 1024 + il * 64 + elem]);
        }
    }

    float* obase = out + (((size_t)(b * NH + h)) * NN + i0 + il) * NN;

    for (int jt = 0; jt < 16; ++jt) {
        const float* np = dbase + (size_t)(jt * 16 + il) * HD + kg * 8;
        float4 d0 = ld4(np), d1 = ld4(np + 4), d2 = ld4(np + 32), d3 = ld4(np + 36);
        int4 ce = *reinterpret_cast<const int4*>(erow + jt * 16 + kg * 4);
        const bf16x8 cb0 = cvt8(d0, d1);
        const bf16x8 cb1 = cvt8(d2, d3);
        f32x4 acc[NT];
        #pragma unroll
        for (int t = 0; t < NT; ++t) {
            acc[t] = (f32x4){0.f, 0.f, 0.f, 0.f};
            acc[t] = __builtin_amdgcn_mfma_f32_16x16x32_bf16(cb0, pa[t][0], acc[t], 0, 0, 0);
            acc[t] = __builtin_amdgcn_mfma_f32_16x16x32_bf16(cb1, pa[t][1], acc[t], 0, 0, 0);
        }
        float4 o;
        #pragma unroll
        for (int r = 0; r < 4; ++r) {
            const int ev = (&ce.x)[r];
            float x;
            if (ev < 0) { x = -1e10f; }
            else {
                x = (ev == 0) ? acc[0][r]
                  : (ev == 1) ? acc[1][r]
                  : (ev == 2) ? acc[2][r]
                  : (ev == 3) ? acc[3][r]
                  :             acc[4][r];
            }
            (&o.x)[r] = (x >= 0.f) ? x : 0.2f * x;
        }
        *reinterpret_cast<float4*>(obase + jt * 16 + kg * 4) = o;
    }
}

extern "C" void kernel_launch(void* const* d_in, const int* in_sizes, int n_in,
                              void* d_out, int out_size, void* d_ws, size_t ws_size,
                              hipStream_t stream) {
    const float* src   = (const float*)d_in[0];
    const float* dst   = (const float*)d_in[1];
    const float* a     = (const float*)d_in[2];
    const int*   edges = (const int*)d_in[3];
    float* out = (float*)d_out;

    const size_t wt_bytes = (size_t)NH * NT * ND * ND * sizeof(__bf16);  // 320 KB
    const size_t t_off    = 1 << 20;                                     // 1 MB align
    const size_t t_bytes  = (size_t)NB * NH * NT * NN * ND * sizeof(__bf16);  // 21 MB

    if (ws_size >= t_off + t_bytes && wt_bytes <= t_off) {
        __bf16* wt = (__bf16*)d_ws;
        __bf16* T  = (__bf16*)((char*)d_ws + t_off);
        const int total = NH * ND * ND * NT;
        prep_w_kernel<<<(total + 255) / 256, 256, 0, stream>>>(a, wt);
        k1_transform<<<2048, 64, 0, stream>>>(src, wt, T);
        k2_scores<<<8192, 256, 0, stream>>>(T, dst, edges, out);
    } else {
        mhea_fused_fallback<<<dim3(NN / 16, NH, NB), 64, 0, stream>>>(
            src, dst, a, edges, out);
    }
}